// Round 14
// baseline (135.920 us; speedup 1.0000x reference)
//
#include <hip/hip_runtime.h>
#include <hip/hip_bf16.h>

#define N_ROWS 8192
#define DIM 256
#define R_BLK 128          // row-slots per block (4 waves x 32)
#define C_CHUNK 256        // cols per block
#define TILE_C 32          // cols per LDS tile
#define N_CHUNKS 32
#define N_ITERS (C_CHUNK / TILE_C)   // 8

typedef __attribute__((ext_vector_type(4))) float f32x4;
typedef __attribute__((ext_vector_type(8))) short bf16x8;

__device__ __forceinline__ void gload_lds16(const void* g, void* l) {
    using gv = const __attribute__((address_space(1))) void*;
    using sv = __attribute__((address_space(3))) void*;
    __builtin_amdgcn_global_load_lds((gv)g, (sv)l, 16, 0, 0);
}

__device__ __forceinline__ ushort f2bf(float v) {
    __hip_bfloat16 h = __float2bfloat16(v);
    return *reinterpret_cast<ushort*>(&h);
}

// ---------------- Kernel A: normalize rows -> bf16 + fused compaction ----------------
// 4 rows/block (1 wave per row). Wave 0 additionally compacts active rows
// (label>=0 && iou>0.5) via ballot + one atomicAdd per block. Slot order is
// non-deterministic but per-row results are slot-invariant -> deterministic output.
__global__ __launch_bounds__(256) void prep_kernel(const float* __restrict__ feat,
                                                   const float* __restrict__ ious,
                                                   const int* __restrict__ labels,
                                                   ushort* __restrict__ fhi,
                                                   int* __restrict__ ridx,
                                                   int* __restrict__ nact) {
    const int row  = blockIdx.x * 4 + (threadIdx.x >> 6);
    const int lane = threadIdx.x & 63;
    const float4 x = reinterpret_cast<const float4*>(feat + (size_t)row * DIM)[lane];
    float ss = x.x * x.x + x.y * x.y + x.z * x.z + x.w * x.w;
#pragma unroll
    for (int off = 32; off; off >>= 1) ss += __shfl_xor(ss, off);
    const float inv = 1.0f / fmaxf(sqrtf(ss), 1e-12f);
    ushort4 h;
    h.x = f2bf(x.x * inv); h.y = f2bf(x.y * inv);
    h.z = f2bf(x.z * inv); h.w = f2bf(x.w * inv);
    reinterpret_cast<ushort4*>(fhi + (size_t)row * DIM)[lane] = h;

    if (threadIdx.x < 64) {           // wave 0 compacts this block's 4 rows
        const int r4 = blockIdx.x * 4 + lane;      // lane 0..3 -> rows
        const bool act = (lane < 4) && (labels[r4] >= 0) && (ious[r4] > 0.5f);
        const unsigned long long mb = __ballot(act);
        const int off = __popcll(mb & ((1ull << lane) - 1ull));
        const int tot = __popcll(mb);
        int base = 0;
        if (lane == 0 && tot) base = atomicAdd(nact, tot);
        base = __shfl(base, 0);
        if (act) ridx[base + off] = r4;
    }
}

// ---------------- Kernel B: fused tiled sim + mask + fixed-max softmax partials ----------------
// grid = 2048 blocks: chunk = bid&31 (256 cols), rowblk = bid>>5 (128 active-row slots)
// Blocks whose slot range is beyond nact exit immediately (~half at typical sparsity).
// Active rows have iou>0.5 & fg -> hi_i always true, ng_i always false.
__global__ __launch_bounds__(256, 4) void main_kernel(const ushort* __restrict__ fhi,
                                                      const float* __restrict__ ious,
                                                      const int* __restrict__ labels,
                                                      const int* __restrict__ ridx,
                                                      const int* __restrict__ nact,
                                                      float* __restrict__ ps_part,
                                                      float* __restrict__ as_part) {
    const int nactive = nact[0];
    const int bid   = blockIdx.x;
    const int rbase = (bid >> 5) * R_BLK;
    if (rbase >= nactive) return;      // uniform early-exit, before any barrier

    const int chunk = bid & (N_CHUNKS - 1);
    const int c0    = chunk * C_CHUNK;

    const int tid  = threadIdx.x;
    const int lane = tid & 63;
    const int w    = tid >> 6;          // 0..3
    const int lrow = lane & 15;
    const int kg   = lane >> 4;         // 0..3
    const int s0   = rbase + w * 32;    // this wave's first row-slot

    __shared__ ushort bt[2][TILE_C][DIM];   // 32 KB, double-buffered B tile
    __shared__ int    lab_s[C_CHUNK];       // 1 KB
    __shared__ float  iou_s[C_CHUNK];       // 1 KB

    // stage column metadata for this chunk (1 per thread)
    lab_s[tid] = labels[c0 + tid];
    iou_s[tid] = ious[c0 + tid];

    // A fragments: two 16-row tiles (gathered via ridx) x 256 k in registers
    bf16x8 av0[8], av1[8];
    {
        const int rowA0 = ridx[min(s0 + lrow,      nactive - 1)];
        const int rowA1 = ridx[min(s0 + 16 + lrow, nactive - 1)];
        const ushort* pa0 = fhi + (size_t)rowA0 * DIM + kg * 8;
        const ushort* pa1 = fhi + (size_t)rowA1 * DIM + kg * 8;
#pragma unroll
        for (int t = 0; t < 8; ++t) {
            av0[t] = *reinterpret_cast<const bf16x8*>(pa0 + t * 32);
            av1[t] = *reinterpret_cast<const bf16x8*>(pa1 + t * 32);
        }
    }

    // row metadata for the 8 row-slots this lane covers (C/D: col=lane&15, row=kg*4+reg)
    int rowm[8]; int labi[8]; float ioui[8]; bool live[8];
#pragma unroll
    for (int m = 0; m < 8; ++m) {
        const int rt = m >> 2, r = m & 3;
        const int slot = s0 + rt * 16 + kg * 4 + r;
        live[m] = slot < nactive;
        const int gi = ridx[min(slot, nactive - 1)];
        rowm[m] = gi;
        labi[m] = live[m] ? labels[gi] : -2;   // -2: matches no column label
        ioui[m] = ious[gi];
    }

    float ps[8], as_[8];
#pragma unroll
    for (int m = 0; m < 8; ++m) { ps[m] = 0.f; as_[m] = 0.f; }

    // staging: tile `it` -> buf; linear LDS dest, pre-swizzled global source (rule #21)
    const char* fhib = (const char*)fhi;
    char* btb = (char*)&bt[0][0][0];
    auto stage = [&](int buf, int it) {
        const int jc = c0 + it * TILE_C;
        const int kb = (tid & 31) * 16;
#pragma unroll
        for (int iss = 0; iss < 4; ++iss) {
            const int row = (tid >> 5) + iss * 8;           // tile-local col 0..31
            const char* src = fhib + (((size_t)(jc + row)) << 9) + (kb ^ ((row & 7) << 4));
            char* dst = btb + buf * 16384 + iss * 4096 + tid * 16;
            gload_lds16(src, dst);
        }
    };

    stage(0, 0);
    __syncthreads();

    const float C1 = 14.42695041f;   // 10*log2(e): e = exp2(acc*C1 - C1) == exp(sim-10)
    int cur = 0;
    for (int it = 0; it < N_ITERS; ++it) {
        if (it + 1 < N_ITERS) stage(cur ^ 1, it + 1);

        const int jcl = it * TILE_C;
        const int labj0 = lab_s[jcl + lrow];
        const int labj1 = lab_s[jcl + 16 + lrow];
        const float iouj0 = iou_s[jcl + lrow];
        const float iouj1 = iou_s[jcl + 16 + lrow];

        f32x4 acc00 = {0.f,0.f,0.f,0.f}, acc01 = {0.f,0.f,0.f,0.f};
        f32x4 acc10 = {0.f,0.f,0.f,0.f}, acc11 = {0.f,0.f,0.f,0.f};
        const char* base = btb + cur * 16384;
        const int swz = (lrow & 7) << 4;
#pragma unroll
        for (int t = 0; t < 8; ++t) {
            const int koff = kg * 16 + t * 64;
            bf16x8 b0 = *reinterpret_cast<const bf16x8*>(base + lrow * 512 + (koff ^ swz));
            bf16x8 b1 = *reinterpret_cast<const bf16x8*>(base + (lrow + 16) * 512 + (koff ^ swz));
            acc00 = __builtin_amdgcn_mfma_f32_16x16x32_bf16(av0[t], b0, acc00, 0, 0, 0);
            acc01 = __builtin_amdgcn_mfma_f32_16x16x32_bf16(av0[t], b1, acc01, 0, 0, 0);
            acc10 = __builtin_amdgcn_mfma_f32_16x16x32_bf16(av1[t], b0, acc10, 0, 0, 0);
            acc11 = __builtin_amdgcn_mfma_f32_16x16x32_bf16(av1[t], b1, acc11, 0, 0, 0);
        }

        // epilogue (active rows: hi_i true, ng_i false, fg_i true):
        //   pos = same && iouj>0.5 && |d|<0.2 && fgj && i!=j
        //   allm = (fgj && i!=j) && (ioum || !same)
#pragma unroll
        for (int rt = 0; rt < 2; ++rt) {
#pragma unroll
            for (int half = 0; half < 2; ++half) {
                const int colg = c0 + jcl + half * 16 + lrow;
                const int labj = half ? labj1 : labj0;
                const float iouj = half ? iouj1 : iouj0;
                const f32x4 acc = rt ? (half ? acc11 : acc10) : (half ? acc01 : acc00);
                const bool fgj = labj >= 0;
                const bool hij = iouj > 0.5f;
#pragma unroll
                for (int r = 0; r < 4; ++r) {
                    const int m  = rt * 4 + r;
                    const bool same = (labi[m] == labj);
                    const bool ioum = hij && (fabsf(iouj - ioui[m]) < 0.2f);
                    const bool pf   = fgj && (rowm[m] != colg);
                    const bool pos  = same && ioum && pf;
                    const bool allm = pf && (ioum || !same);
                    const float e = allm ? exp2f(fmaf(acc[r], C1, -C1)) : 0.0f;
                    as_[m] += e;
                    ps[m]  += pos ? e : 0.0f;
                }
            }
        }
        __syncthreads();
        cur ^= 1;
    }

    // reduce over the 16 lanes (lrow) holding col-slices of the same rows
#pragma unroll
    for (int off = 1; off < 16; off <<= 1) {
#pragma unroll
        for (int m = 0; m < 8; ++m) {
            ps[m]  += __shfl_xor(ps[m], off);
            as_[m] += __shfl_xor(as_[m], off);
        }
    }

    if (lrow == 0) {
#pragma unroll
        for (int m = 0; m < 8; ++m) {
            if (live[m]) {
                const int idx = chunk * N_ROWS + rowm[m];
                ps_part[idx] = ps[m];
                as_part[idx] = as_[m];
            }
        }
    }
}

// ---------------- Kernel C: combine chunk partials -> per-row loss ----------------
// Only rows with (label>=0 && iou>0.5) have written partials; others gated off.
// any-pos <=> P>0 ; any-neg <=> A>P (pos/neg disjoint for active rows)
__global__ __launch_bounds__(256) void combine_kernel(const float* __restrict__ ps_part,
                                                      const float* __restrict__ as_part,
                                                      const float* __restrict__ ious,
                                                      const int* __restrict__ labels,
                                                      float* __restrict__ loss_arr,
                                                      float* __restrict__ valid_arr) {
    const int row = blockIdx.x * 256 + threadIdx.x;
    const bool act = (labels[row] >= 0) && (ious[row] > 0.5f);
    float loss = 0.f, vld = 0.f;
    if (act) {
        float P = 0.f, A = 0.f;
#pragma unroll
        for (int c = 0; c < N_CHUNKS; ++c) {
            P += ps_part[c * N_ROWS + row];
            A += as_part[c * N_ROWS + row];
        }
        const float psc = fminf(fmaxf(P, 1e-6f), 1e6f);
        const float asc = fminf(fmaxf(A, 1e-6f), 1e6f);
        const bool valid = (P > 0.0f) && (A > P);
        loss = valid ? fminf(__logf(asc) - __logf(psc), 10.0f) : 0.0f;
        vld  = valid ? 1.0f : 0.0f;
    }
    loss_arr[row]  = loss;
    valid_arr[row] = vld;
}

// ---------------- Kernel D: final mean ----------------
__global__ __launch_bounds__(256) void reduce_kernel(const float* __restrict__ loss_arr,
                                                     const float* __restrict__ valid_arr,
                                                     float* __restrict__ out) {
    const int tid = threadIdx.x;
    float tl = 0.f, tc = 0.f;
    for (int i = tid; i < N_ROWS; i += 256) { tl += loss_arr[i]; tc += valid_arr[i]; }
#pragma unroll
    for (int off = 32; off; off >>= 1) { tl += __shfl_down(tl, off); tc += __shfl_down(tc, off); }
    __shared__ float sl[4], sc[4];
    const int wid = tid >> 6;
    if ((tid & 63) == 0) { sl[wid] = tl; sc[wid] = tc; }
    __syncthreads();
    if (tid == 0) {
        float T = sl[0] + sl[1] + sl[2] + sl[3];
        float C = sc[0] + sc[1] + sc[2] + sc[3];
        out[0] = (C > 0.f) ? (T / C) : 0.0f;
    }
}

extern "C" void kernel_launch(void* const* d_in, const int* in_sizes, int n_in,
                              void* d_out, int out_size, void* d_ws, size_t ws_size,
                              hipStream_t stream) {
    const float* feat   = (const float*)d_in[0];
    const float* ious   = (const float*)d_in[1];
    const int*   labels = (const int*)d_in[2];
    float* out = (float*)d_out;

    ushort* fhi = (ushort*)d_ws;                                     // 4 MB
    float*  ps_part = (float*)(fhi + (size_t)N_ROWS * DIM);          // 1 MB
    float*  as_part = ps_part + (size_t)N_CHUNKS * N_ROWS;           // 1 MB
    float*  loss_arr  = as_part + (size_t)N_CHUNKS * N_ROWS;         // 32 KB
    float*  valid_arr = loss_arr + N_ROWS;                           // 32 KB
    int*    ridx = (int*)(valid_arr + N_ROWS);                       // 32 KB
    int*    nact = ridx + N_ROWS;                                    // 4 B

    hipMemsetAsync(nact, 0, sizeof(int), stream);
    prep_kernel<<<N_ROWS / 4, 256, 0, stream>>>(feat, ious, labels, fhi, ridx, nact);
    main_kernel<<<(N_ROWS / R_BLK) * N_CHUNKS, 256, 0, stream>>>(fhi, ious, labels,
                                                                 ridx, nact, ps_part, as_part);
    combine_kernel<<<N_ROWS / 256, 256, 0, stream>>>(ps_part, as_part, ious, labels,
                                                     loss_arr, valid_arr);
    reduce_kernel<<<1, 256, 0, stream>>>(loss_arr, valid_arr, out);
}

// Round 15
// 83.455 us; speedup vs baseline: 1.6287x; 1.6287x over previous
//
#include <hip/hip_runtime.h>
#include <hip/hip_bf16.h>

#define N_ROWS 8192
#define DIM 256
#define R_BLK 128          // row-slots per block (4 waves x 32)
#define C_CHUNK 256        // cols per block
#define TILE_C 32          // cols per LDS tile
#define N_CHUNKS 32
#define N_ITERS (C_CHUNK / TILE_C)   // 8

typedef __attribute__((ext_vector_type(4))) float f32x4;
typedef __attribute__((ext_vector_type(8))) short bf16x8;

__device__ __forceinline__ void gload_lds16(const void* g, void* l) {
    using gv = const __attribute__((address_space(1))) void*;
    using sv = __attribute__((address_space(3))) void*;
    __builtin_amdgcn_global_load_lds((gv)g, (sv)l, 16, 0, 0);
}

__device__ __forceinline__ ushort f2bf(float v) {
    __hip_bfloat16 h = __float2bfloat16(v);
    return *reinterpret_cast<ushort*>(&h);
}

// ---------------- Kernel A: normalize rows -> bf16 + fused compaction ----------------
__global__ __launch_bounds__(256) void prep_kernel(const float* __restrict__ feat,
                                                   const float* __restrict__ ious,
                                                   const int* __restrict__ labels,
                                                   ushort* __restrict__ fhi,
                                                   int* __restrict__ ridx,
                                                   int* __restrict__ nact) {
    const int row  = blockIdx.x * 4 + (threadIdx.x >> 6);
    const int lane = threadIdx.x & 63;
    const float4 x = reinterpret_cast<const float4*>(feat + (size_t)row * DIM)[lane];
    float ss = x.x * x.x + x.y * x.y + x.z * x.z + x.w * x.w;
#pragma unroll
    for (int off = 32; off; off >>= 1) ss += __shfl_xor(ss, off);
    const float inv = 1.0f / fmaxf(sqrtf(ss), 1e-12f);
    ushort4 h;
    h.x = f2bf(x.x * inv); h.y = f2bf(x.y * inv);
    h.z = f2bf(x.z * inv); h.w = f2bf(x.w * inv);
    reinterpret_cast<ushort4*>(fhi + (size_t)row * DIM)[lane] = h;

    if (threadIdx.x < 64) {           // wave 0 compacts this block's 4 rows
        const int r4 = blockIdx.x * 4 + lane;      // lane 0..3 -> rows
        const bool act = (lane < 4) && (labels[r4] >= 0) && (ious[r4] > 0.5f);
        const unsigned long long mb = __ballot(act);
        const int off = __popcll(mb & ((1ull << lane) - 1ull));
        const int tot = __popcll(mb);
        int base = 0;
        if (lane == 0 && tot) base = atomicAdd(nact, tot);
        base = __shfl(base, 0);
        if (act) ridx[base + off] = r4;
    }
}

// ---------------- Kernel B: fused tiled sim + mask + fixed-max softmax partials ----------------
// grid = 2048 blocks: chunk = bid&31 (256 cols), rowblk = bid>>5 (128 active-row slots)
// Blocks beyond nact exit immediately. Active rows: iou>0.5 & fg.
// NOTE: min_waves_per_EU = 3 (NOT 4): 4 caps VGPR at 128 and spills the 64-VGPR
// A-fragment arrays to scratch (round-14 post-mortem: FETCH 154 MB, 2x slower).
__global__ __launch_bounds__(256, 3) void main_kernel(const ushort* __restrict__ fhi,
                                                      const float* __restrict__ ious,
                                                      const int* __restrict__ labels,
                                                      const int* __restrict__ ridx,
                                                      const int* __restrict__ nact,
                                                      float* __restrict__ ps_part,
                                                      float* __restrict__ as_part) {
    const int nactive = nact[0];
    const int bid   = blockIdx.x;
    const int rbase = (bid >> 5) * R_BLK;
    if (rbase >= nactive) return;      // uniform early-exit, before any barrier

    const int chunk = bid & (N_CHUNKS - 1);
    const int c0    = chunk * C_CHUNK;

    const int tid  = threadIdx.x;
    const int lane = tid & 63;
    const int w    = tid >> 6;          // 0..3
    const int lrow = lane & 15;
    const int kg   = lane >> 4;         // 0..3
    const int s0   = rbase + w * 32;    // this wave's first row-slot

    __shared__ ushort bt[2][TILE_C][DIM];   // 32 KB, double-buffered B tile
    __shared__ int    lab_s[C_CHUNK];       // 1 KB
    __shared__ float  iou_s[C_CHUNK];       // 1 KB

    // stage column metadata for this chunk (1 per thread)
    lab_s[tid] = labels[c0 + tid];
    iou_s[tid] = ious[c0 + tid];

    // A fragments: two 16-row tiles (gathered via ridx) x 256 k in registers
    bf16x8 av0[8], av1[8];
    {
        const int rowA0 = ridx[min(s0 + lrow,      nactive - 1)];
        const int rowA1 = ridx[min(s0 + 16 + lrow, nactive - 1)];
        const ushort* pa0 = fhi + (size_t)rowA0 * DIM + kg * 8;
        const ushort* pa1 = fhi + (size_t)rowA1 * DIM + kg * 8;
#pragma unroll
        for (int t = 0; t < 8; ++t) {
            av0[t] = *reinterpret_cast<const bf16x8*>(pa0 + t * 32);
            av1[t] = *reinterpret_cast<const bf16x8*>(pa1 + t * 32);
        }
    }

    // row metadata for the 8 row-slots this lane covers (C/D: col=lane&15, row=kg*4+reg)
    int rowm[8]; int labi[8]; float ioui[8]; bool live[8];
#pragma unroll
    for (int m = 0; m < 8; ++m) {
        const int rt = m >> 2, r = m & 3;
        const int slot = s0 + rt * 16 + kg * 4 + r;
        live[m] = slot < nactive;
        const int gi = ridx[min(slot, nactive - 1)];
        rowm[m] = gi;
        labi[m] = live[m] ? labels[gi] : -2;   // -2: matches no column label
        ioui[m] = ious[gi];
    }

    float ps[8], as_[8];
#pragma unroll
    for (int m = 0; m < 8; ++m) { ps[m] = 0.f; as_[m] = 0.f; }

    // staging: tile `it` -> buf; linear LDS dest, pre-swizzled global source (rule #21)
    const char* fhib = (const char*)fhi;
    char* btb = (char*)&bt[0][0][0];
    auto stage = [&](int buf, int it) {
        const int jc = c0 + it * TILE_C;
        const int kb = (tid & 31) * 16;
#pragma unroll
        for (int iss = 0; iss < 4; ++iss) {
            const int row = (tid >> 5) + iss * 8;           // tile-local col 0..31
            const char* src = fhib + (((size_t)(jc + row)) << 9) + (kb ^ ((row & 7) << 4));
            char* dst = btb + buf * 16384 + iss * 4096 + tid * 16;
            gload_lds16(src, dst);
        }
    };

    stage(0, 0);
    __syncthreads();

    const float C1 = 14.42695041f;   // 10*log2(e): e = exp2(acc*C1 - C1) == exp(sim-10)
    int cur = 0;
    for (int it = 0; it < N_ITERS; ++it) {
        if (it + 1 < N_ITERS) stage(cur ^ 1, it + 1);

        const int jcl = it * TILE_C;
        const int labj0 = lab_s[jcl + lrow];
        const int labj1 = lab_s[jcl + 16 + lrow];
        const float iouj0 = iou_s[jcl + lrow];
        const float iouj1 = iou_s[jcl + 16 + lrow];

        f32x4 acc00 = {0.f,0.f,0.f,0.f}, acc01 = {0.f,0.f,0.f,0.f};
        f32x4 acc10 = {0.f,0.f,0.f,0.f}, acc11 = {0.f,0.f,0.f,0.f};
        const char* base = btb + cur * 16384;
        const int swz = (lrow & 7) << 4;
#pragma unroll
        for (int t = 0; t < 8; ++t) {
            const int koff = kg * 16 + t * 64;
            bf16x8 b0 = *reinterpret_cast<const bf16x8*>(base + lrow * 512 + (koff ^ swz));
            bf16x8 b1 = *reinterpret_cast<const bf16x8*>(base + (lrow + 16) * 512 + (koff ^ swz));
            acc00 = __builtin_amdgcn_mfma_f32_16x16x32_bf16(av0[t], b0, acc00, 0, 0, 0);
            acc01 = __builtin_amdgcn_mfma_f32_16x16x32_bf16(av0[t], b1, acc01, 0, 0, 0);
            acc10 = __builtin_amdgcn_mfma_f32_16x16x32_bf16(av1[t], b0, acc10, 0, 0, 0);
            acc11 = __builtin_amdgcn_mfma_f32_16x16x32_bf16(av1[t], b1, acc11, 0, 0, 0);
        }

        // epilogue (active rows: hi_i true, ng_i false, fg_i true):
        //   pos = same && iouj>0.5 && |d|<0.2 && fgj && i!=j
        //   allm = (fgj && i!=j) && (ioum || !same)
#pragma unroll
        for (int rt = 0; rt < 2; ++rt) {
#pragma unroll
            for (int half = 0; half < 2; ++half) {
                const int colg = c0 + jcl + half * 16 + lrow;
                const int labj = half ? labj1 : labj0;
                const float iouj = half ? iouj1 : iouj0;
                const f32x4 acc = rt ? (half ? acc11 : acc10) : (half ? acc01 : acc00);
                const bool fgj = labj >= 0;
                const bool hij = iouj > 0.5f;
#pragma unroll
                for (int r = 0; r < 4; ++r) {
                    const int m  = rt * 4 + r;
                    const bool same = (labi[m] == labj);
                    const bool ioum = hij && (fabsf(iouj - ioui[m]) < 0.2f);
                    const bool pf   = fgj && (rowm[m] != colg);
                    const bool pos  = same && ioum && pf;
                    const bool allm = pf && (ioum || !same);
                    const float e = allm ? exp2f(fmaf(acc[r], C1, -C1)) : 0.0f;
                    as_[m] += e;
                    ps[m]  += pos ? e : 0.0f;
                }
            }
        }
        __syncthreads();
        cur ^= 1;
    }

    // reduce over the 16 lanes (lrow) holding col-slices of the same rows
#pragma unroll
    for (int off = 1; off < 16; off <<= 1) {
#pragma unroll
        for (int m = 0; m < 8; ++m) {
            ps[m]  += __shfl_xor(ps[m], off);
            as_[m] += __shfl_xor(as_[m], off);
        }
    }

    if (lrow == 0) {
#pragma unroll
        for (int m = 0; m < 8; ++m) {
            if (live[m]) {
                const int idx = chunk * N_ROWS + rowm[m];
                ps_part[idx] = ps[m];
                as_part[idx] = as_[m];
            }
        }
    }
}

// ---------------- Kernel C: combine chunk partials -> per-row loss -> mean (fused) ----------------
// 32 blocks x 256 rows. Each block reduces its rows to partial {T,C}; the last
// block to finish sums the 32 slots in fixed index order (deterministic) and writes out.
__global__ __launch_bounds__(256) void combine_kernel(const float* __restrict__ ps_part,
                                                      const float* __restrict__ as_part,
                                                      const float* __restrict__ ious,
                                                      const int* __restrict__ labels,
                                                      float* __restrict__ partT,
                                                      float* __restrict__ partC,
                                                      int* __restrict__ done,
                                                      float* __restrict__ out) {
    const int tid = threadIdx.x;
    const int row = blockIdx.x * 256 + tid;
    const bool act = (labels[row] >= 0) && (ious[row] > 0.5f);
    float loss = 0.f, vld = 0.f;
    if (act) {
        float P = 0.f, A = 0.f;
#pragma unroll
        for (int c = 0; c < N_CHUNKS; ++c) {
            P += ps_part[c * N_ROWS + row];
            A += as_part[c * N_ROWS + row];
        }
        const float psc = fminf(fmaxf(P, 1e-6f), 1e6f);
        const float asc = fminf(fmaxf(A, 1e-6f), 1e6f);
        const bool valid = (P > 0.0f) && (A > P);
        loss = valid ? fminf(__logf(asc) - __logf(psc), 10.0f) : 0.0f;
        vld  = valid ? 1.0f : 0.0f;
    }
    // block reduction
    float tl = loss, tc = vld;
#pragma unroll
    for (int off = 32; off; off >>= 1) { tl += __shfl_down(tl, off); tc += __shfl_down(tc, off); }
    __shared__ float sl[4], sc[4];
    const int wid = tid >> 6;
    if ((tid & 63) == 0) { sl[wid] = tl; sc[wid] = tc; }
    __syncthreads();
    if (tid == 0) {
        partT[blockIdx.x] = sl[0] + sl[1] + sl[2] + sl[3];
        partC[blockIdx.x] = sc[0] + sc[1] + sc[2] + sc[3];
        __threadfence();
        const int prev = atomicAdd(done, 1);
        if (prev == (int)gridDim.x - 1) {      // last block finalizes
            __threadfence();
            float T = 0.f, C = 0.f;
#pragma unroll
            for (int b = 0; b < N_ROWS / 256; ++b) { T += partT[b]; C += partC[b]; }
            out[0] = (C > 0.f) ? (T / C) : 0.0f;
        }
    }
}

extern "C" void kernel_launch(void* const* d_in, const int* in_sizes, int n_in,
                              void* d_out, int out_size, void* d_ws, size_t ws_size,
                              hipStream_t stream) {
    const float* feat   = (const float*)d_in[0];
    const float* ious   = (const float*)d_in[1];
    const int*   labels = (const int*)d_in[2];
    float* out = (float*)d_out;

    ushort* fhi = (ushort*)d_ws;                                     // 4 MB
    float*  ps_part = (float*)(fhi + (size_t)N_ROWS * DIM);          // 1 MB
    float*  as_part = ps_part + (size_t)N_CHUNKS * N_ROWS;           // 1 MB
    int*    ridx = (int*)(as_part + (size_t)N_CHUNKS * N_ROWS);      // 32 KB
    int*    ctrs = ridx + N_ROWS;                                    // nact, done
    float*  partT = (float*)(ctrs + 2);                              // 32 floats
    float*  partC = partT + (N_ROWS / 256);                          // 32 floats

    hipMemsetAsync(ctrs, 0, 2 * sizeof(int), stream);
    prep_kernel<<<N_ROWS / 4, 256, 0, stream>>>(feat, ious, labels, fhi, ridx, ctrs);
    main_kernel<<<(N_ROWS / R_BLK) * N_CHUNKS, 256, 0, stream>>>(fhi, ious, labels,
                                                                 ridx, ctrs, ps_part, as_part);
    combine_kernel<<<N_ROWS / 256, 256, 0, stream>>>(ps_part, as_part, ious, labels,
                                                     partT, partC, ctrs + 1, out);
}

// Round 16
// 69.341 us; speedup vs baseline: 1.9602x; 1.2035x over previous
//
#include <hip/hip_runtime.h>
#include <hip/hip_bf16.h>

#define N_ROWS 8192
#define DIM 256
#define R_BLK 128          // row-slots per block (4 waves x 32)
#define C_CHUNK 512        // cols per block
#define TILE_C 32          // cols per LDS tile
#define N_CHUNKS 16
#define N_ITERS (C_CHUNK / TILE_C)   // 16

typedef __attribute__((ext_vector_type(4))) float f32x4;
typedef __attribute__((ext_vector_type(8))) short bf16x8;

__device__ __forceinline__ void gload_lds16(const void* g, void* l) {
    using gv = const __attribute__((address_space(1))) void*;
    using sv = __attribute__((address_space(3))) void*;
    __builtin_amdgcn_global_load_lds((gv)g, (sv)l, 16, 0, 0);
}

__device__ __forceinline__ ushort f2bf(float v) {
    __hip_bfloat16 h = __float2bfloat16(v);
    return *reinterpret_cast<ushort*>(&h);
}

// ---------------- Kernel A: normalize rows -> bf16 (1 wave per row, no LDS, no atomics) ----------------
__global__ __launch_bounds__(256) void prep_kernel(const float* __restrict__ feat,
                                                   ushort* __restrict__ fhi) {
    const int row  = blockIdx.x * 4 + (threadIdx.x >> 6);
    const int lane = threadIdx.x & 63;
    const float4 x = reinterpret_cast<const float4*>(feat + (size_t)row * DIM)[lane];
    float ss = x.x * x.x + x.y * x.y + x.z * x.z + x.w * x.w;
#pragma unroll
    for (int off = 32; off; off >>= 1) ss += __shfl_xor(ss, off);
    const float inv = 1.0f / fmaxf(sqrtf(ss), 1e-12f);
    ushort4 h;
    h.x = f2bf(x.x * inv); h.y = f2bf(x.y * inv);
    h.z = f2bf(x.z * inv); h.w = f2bf(x.w * inv);
    reinterpret_cast<ushort4*>(fhi + (size_t)row * DIM)[lane] = h;
}

// ---------------- Kernel A2: compact active rows (single block: 32 LDS atomics, not 2048 global) ----------------
// Slot order non-deterministic but per-row results are slot-invariant -> deterministic output.
__global__ __launch_bounds__(256) void compact_kernel(const float* __restrict__ ious,
                                                      const int* __restrict__ labels,
                                                      int* __restrict__ ridx,
                                                      int* __restrict__ nact) {
    __shared__ int cnt;
    if (threadIdx.x == 0) cnt = 0;
    __syncthreads();
    const int lane = threadIdx.x & 63;
    for (int i = threadIdx.x; i < N_ROWS; i += 256) {
        const bool act = (labels[i] >= 0) && (ious[i] > 0.5f);
        const unsigned long long mb = __ballot(act);
        const int off = __popcll(mb & ((1ull << lane) - 1ull));
        const int tot = __popcll(mb);
        int base = 0;
        if (lane == 0 && tot) base = atomicAdd(&cnt, tot);
        base = __shfl(base, 0);
        if (act) ridx[base + off] = i;
    }
    __syncthreads();
    if (threadIdx.x == 0) nact[0] = cnt;
}

// ---------------- Kernel B: fused tiled sim + mask + fixed-max softmax partials ----------------
// grid = 1024 blocks: chunk = bid&15 (512 cols), rowblk = bid>>4 (128 active-row slots)
// B tile stored in MFMA-FRAGMENT ORDER: chunk index L = half*512 + t*64 + lrow*4 + kg, 16B each.
// A wave's read at fixed (t,half) is lane-linear over contiguous 1KB -> zero bank conflicts,
// and read addresses are base + t*1024 compile-time immediates (no XOR math).
// launch_bounds (256,3): 4 spills the 64-VGPR A-fragments (round-14 post-mortem).
__global__ __launch_bounds__(256, 3) void main_kernel(const ushort* __restrict__ fhi,
                                                      const float* __restrict__ ious,
                                                      const int* __restrict__ labels,
                                                      const int* __restrict__ ridx,
                                                      const int* __restrict__ nact,
                                                      float* __restrict__ ps_part,
                                                      float* __restrict__ as_part) {
    const int nactive = nact[0];
    const int bid   = blockIdx.x;
    const int rbase = (bid >> 4) * R_BLK;
    if (rbase >= nactive) return;      // uniform early-exit, before any barrier

    const int chunk = bid & (N_CHUNKS - 1);
    const int c0    = chunk * C_CHUNK;

    const int tid  = threadIdx.x;
    const int lane = tid & 63;
    const int w    = tid >> 6;          // 0..3
    const int lrow = lane & 15;
    const int kg   = lane >> 4;         // 0..3
    const int s0   = rbase + w * 32;    // this wave's first row-slot

    __shared__ bf16x8 bt[2][1024];          // 32 KB, double-buffered fragment-ordered B tile
    __shared__ int    lab_s[C_CHUNK];       // 2 KB
    __shared__ float  iou_s[C_CHUNK];       // 2 KB

    // stage column metadata for this chunk (2 per thread)
#pragma unroll
    for (int i = tid; i < C_CHUNK; i += 256) {
        lab_s[i] = labels[c0 + i];
        iou_s[i] = ious[c0 + i];
    }

    // A fragments: two 16-row tiles (gathered via ridx) x 256 k in registers
    bf16x8 av0[8], av1[8];
    {
        const int rowA0 = ridx[min(s0 + lrow,      nactive - 1)];
        const int rowA1 = ridx[min(s0 + 16 + lrow, nactive - 1)];
        const ushort* pa0 = fhi + (size_t)rowA0 * DIM + kg * 8;
        const ushort* pa1 = fhi + (size_t)rowA1 * DIM + kg * 8;
#pragma unroll
        for (int t = 0; t < 8; ++t) {
            av0[t] = *reinterpret_cast<const bf16x8*>(pa0 + t * 32);
            av1[t] = *reinterpret_cast<const bf16x8*>(pa1 + t * 32);
        }
    }

    // row metadata for the 8 row-slots this lane covers (C/D: col=lane&15, row=kg*4+reg)
    int rowm[8]; int labi[8]; float ioui[8]; bool live[8];
#pragma unroll
    for (int m = 0; m < 8; ++m) {
        const int rt = m >> 2, r = m & 3;
        const int slot = s0 + rt * 16 + kg * 4 + r;
        live[m] = slot < nactive;
        const int gi = ridx[min(slot, nactive - 1)];
        rowm[m] = gi;
        labi[m] = live[m] ? labels[gi] : -2;   // -2: matches no column label
        ioui[m] = ious[gi];
    }

    float ps[8], as_[8];
#pragma unroll
    for (int m = 0; m < 8; ++m) { ps[m] = 0.f; as_[m] = 0.f; }

    // staging in fragment order: LDS chunk L <- global fragment (half,t,lr,kg2)
    const char* fhib = (const char*)fhi;
    char* btb = (char*)&bt[0][0];
    auto stage = [&](int buf, int it) {
        const int jc = c0 + it * TILE_C;
#pragma unroll
        for (int iss = 0; iss < 4; ++iss) {
            const int L    = iss * 256 + tid;      // 0..1023
            const int half = L >> 9;
            const int rem  = L & 511;
            const int t    = rem >> 6;
            const int lr   = (rem >> 2) & 15;
            const int kg2  = rem & 3;
            const char* src = fhib + (((size_t)(jc + half * 16 + lr)) << 9) + (kg2 * 16 + t * 64);
            char* dst = btb + buf * 16384 + iss * 4096 + tid * 16;
            gload_lds16(src, dst);
        }
    };

    stage(0, 0);
    __syncthreads();

    const float C1 = 14.42695041f;   // 10*log2(e): e = exp2(acc*C1 - C1) == exp(sim-10)
    int cur = 0;
    for (int it = 0; it < N_ITERS; ++it) {
        if (it + 1 < N_ITERS) stage(cur ^ 1, it + 1);

        const int jcl = it * TILE_C;
        const int labj0 = lab_s[jcl + lrow];
        const int labj1 = lab_s[jcl + 16 + lrow];
        const float iouj0 = iou_s[jcl + lrow];
        const float iouj1 = iou_s[jcl + 16 + lrow];

        f32x4 acc00 = {0.f,0.f,0.f,0.f}, acc01 = {0.f,0.f,0.f,0.f};
        f32x4 acc10 = {0.f,0.f,0.f,0.f}, acc11 = {0.f,0.f,0.f,0.f};
        const char* lbase = btb + cur * 16384 + ((lrow * 4 + kg) << 4);
#pragma unroll
        for (int t = 0; t < 8; ++t) {
            bf16x8 b0 = *reinterpret_cast<const bf16x8*>(lbase + t * 1024);
            bf16x8 b1 = *reinterpret_cast<const bf16x8*>(lbase + 8192 + t * 1024);
            acc00 = __builtin_amdgcn_mfma_f32_16x16x32_bf16(av0[t], b0, acc00, 0, 0, 0);
            acc01 = __builtin_amdgcn_mfma_f32_16x16x32_bf16(av0[t], b1, acc01, 0, 0, 0);
            acc10 = __builtin_amdgcn_mfma_f32_16x16x32_bf16(av1[t], b0, acc10, 0, 0, 0);
            acc11 = __builtin_amdgcn_mfma_f32_16x16x32_bf16(av1[t], b1, acc11, 0, 0, 0);
        }

        // epilogue (active rows: hi_i true, ng_i false, fg_i true):
        //   pos = same && iouj>0.5 && |d|<0.2 && fgj && i!=j
        //   allm = (fgj && i!=j) && (ioum || !same)
#pragma unroll
        for (int rt = 0; rt < 2; ++rt) {
#pragma unroll
            for (int half = 0; half < 2; ++half) {
                const int colg = c0 + jcl + half * 16 + lrow;
                const int labj = half ? labj1 : labj0;
                const float iouj = half ? iouj1 : iouj0;
                const f32x4 acc = rt ? (half ? acc11 : acc10) : (half ? acc01 : acc00);
                const bool fgj = labj >= 0;
                const bool hij = iouj > 0.5f;
#pragma unroll
                for (int r = 0; r < 4; ++r) {
                    const int m  = rt * 4 + r;
                    const bool same = (labi[m] == labj);
                    const bool ioum = hij && (fabsf(iouj - ioui[m]) < 0.2f);
                    const bool pf   = fgj && (rowm[m] != colg);
                    const bool pos  = same && ioum && pf;
                    const bool allm = pf && (ioum || !same);
                    const float e = allm ? exp2f(fmaf(acc[r], C1, -C1)) : 0.0f;
                    as_[m] += e;
                    ps[m]  += pos ? e : 0.0f;
                }
            }
        }
        __syncthreads();
        cur ^= 1;
    }

    // reduce over the 16 lanes (lrow) holding col-slices of the same rows
#pragma unroll
    for (int off = 1; off < 16; off <<= 1) {
#pragma unroll
        for (int m = 0; m < 8; ++m) {
            ps[m]  += __shfl_xor(ps[m], off);
            as_[m] += __shfl_xor(as_[m], off);
        }
    }

    if (lrow == 0) {
#pragma unroll
        for (int m = 0; m < 8; ++m) {
            if (live[m]) {
                const int idx = chunk * N_ROWS + rowm[m];
                ps_part[idx] = ps[m];
                as_part[idx] = as_[m];
            }
        }
    }
}

// ---------------- Kernel C: combine chunk partials -> per-row loss -> mean (fused) ----------------
__global__ __launch_bounds__(256) void combine_kernel(const float* __restrict__ ps_part,
                                                      const float* __restrict__ as_part,
                                                      const float* __restrict__ ious,
                                                      const int* __restrict__ labels,
                                                      float* __restrict__ partT,
                                                      float* __restrict__ partC,
                                                      int* __restrict__ done,
                                                      float* __restrict__ out) {
    const int tid = threadIdx.x;
    const int row = blockIdx.x * 256 + tid;
    const bool act = (labels[row] >= 0) && (ious[row] > 0.5f);
    float loss = 0.f, vld = 0.f;
    if (act) {
        float P = 0.f, A = 0.f;
#pragma unroll
        for (int c = 0; c < N_CHUNKS; ++c) {
            P += ps_part[c * N_ROWS + row];
            A += as_part[c * N_ROWS + row];
        }
        const float psc = fminf(fmaxf(P, 1e-6f), 1e6f);
        const float asc = fminf(fmaxf(A, 1e-6f), 1e6f);
        const bool valid = (P > 0.0f) && (A > P);
        loss = valid ? fminf(__logf(asc) - __logf(psc), 10.0f) : 0.0f;
        vld  = valid ? 1.0f : 0.0f;
    }
    float tl = loss, tc = vld;
#pragma unroll
    for (int off = 32; off; off >>= 1) { tl += __shfl_down(tl, off); tc += __shfl_down(tc, off); }
    __shared__ float sl[4], sc[4];
    const int wid = tid >> 6;
    if ((tid & 63) == 0) { sl[wid] = tl; sc[wid] = tc; }
    __syncthreads();
    if (tid == 0) {
        partT[blockIdx.x] = sl[0] + sl[1] + sl[2] + sl[3];
        partC[blockIdx.x] = sc[0] + sc[1] + sc[2] + sc[3];
        __threadfence();
        const int prev = atomicAdd(done, 1);
        if (prev == (int)gridDim.x - 1) {      // last block finalizes (fixed order: deterministic)
            __threadfence();
            float T = 0.f, C = 0.f;
#pragma unroll
            for (int b = 0; b < N_ROWS / 256; ++b) { T += partT[b]; C += partC[b]; }
            out[0] = (C > 0.f) ? (T / C) : 0.0f;
        }
    }
}

extern "C" void kernel_launch(void* const* d_in, const int* in_sizes, int n_in,
                              void* d_out, int out_size, void* d_ws, size_t ws_size,
                              hipStream_t stream) {
    const float* feat   = (const float*)d_in[0];
    const float* ious   = (const float*)d_in[1];
    const int*   labels = (const int*)d_in[2];
    float* out = (float*)d_out;

    ushort* fhi = (ushort*)d_ws;                                     // 4 MB
    float*  ps_part = (float*)(fhi + (size_t)N_ROWS * DIM);          // 512 KB
    float*  as_part = ps_part + (size_t)N_CHUNKS * N_ROWS;           // 512 KB
    int*    ridx = (int*)(as_part + (size_t)N_CHUNKS * N_ROWS);      // 32 KB
    int*    ctrs = ridx + N_ROWS;                                    // nact, done
    float*  partT = (float*)(ctrs + 2);                              // 32 floats
    float*  partC = partT + (N_ROWS / 256);                          // 32 floats

    hipMemsetAsync(ctrs, 0, 2 * sizeof(int), stream);
    prep_kernel<<<N_ROWS / 4, 256, 0, stream>>>(feat, fhi);
    compact_kernel<<<1, 256, 0, stream>>>(ious, labels, ridx, ctrs);
    main_kernel<<<(N_ROWS / R_BLK) * N_CHUNKS, 256, 0, stream>>>(fhi, ious, labels,
                                                                 ridx, ctrs, ps_part, as_part);
    combine_kernel<<<N_ROWS / 256, 256, 0, stream>>>(ps_part, as_part, ious, labels,
                                                     partT, partC, ctrs + 1, out);
}

// Round 18
// 59.524 us; speedup vs baseline: 2.2834x; 1.1649x over previous
//
#include <hip/hip_runtime.h>
#include <hip/hip_bf16.h>

#define N_ROWS 8192
#define DIM 256
#define R_BLK 128          // row-slots per block (4 waves x 32)
#define C_CHUNK 512        // cols per block
#define TILE_C 32          // cols per LDS tile
#define N_CHUNKS 16
#define N_ITERS (C_CHUNK / TILE_C)   // 16

typedef __attribute__((ext_vector_type(4))) float f32x4;
typedef __attribute__((ext_vector_type(8))) short bf16x8;

__device__ __forceinline__ void gload_lds16(const void* g, void* l) {
    using gv = const __attribute__((address_space(1))) void*;
    using sv = __attribute__((address_space(3))) void*;
    __builtin_amdgcn_global_load_lds((gv)g, (sv)l, 16, 0, 0);
}

__device__ __forceinline__ ushort f2bf(float v) {
    __hip_bfloat16 h = __float2bfloat16(v);
    return *reinterpret_cast<ushort*>(&h);
}

// ---------------- Kernel A: normalize rows -> bf16 + per-block compaction ----------------
// 256 blocks x 32 contiguous rows. One atomicAdd per block (256 total, spread out).
// ridx slot order non-deterministic; per-row results are slot-invariant -> deterministic output.
__global__ __launch_bounds__(256) void prep_kernel(const float* __restrict__ feat,
                                                   const float* __restrict__ ious,
                                                   const int* __restrict__ labels,
                                                   ushort* __restrict__ fhi,
                                                   int* __restrict__ ridx,
                                                   int* __restrict__ nact) {
    const int wid  = threadIdx.x >> 6;
    const int lane = threadIdx.x & 63;
#pragma unroll
    for (int r8 = 0; r8 < 8; ++r8) {
        const int row = blockIdx.x * 32 + r8 * 4 + wid;
        const float4 x = reinterpret_cast<const float4*>(feat + (size_t)row * DIM)[lane];
        float ss = x.x * x.x + x.y * x.y + x.z * x.z + x.w * x.w;
#pragma unroll
        for (int off = 32; off; off >>= 1) ss += __shfl_xor(ss, off);
        const float inv = 1.0f / fmaxf(sqrtf(ss), 1e-12f);
        ushort4 h;
        h.x = f2bf(x.x * inv); h.y = f2bf(x.y * inv);
        h.z = f2bf(x.z * inv); h.w = f2bf(x.w * inv);
        reinterpret_cast<ushort4*>(fhi + (size_t)row * DIM)[lane] = h;
    }
    if (threadIdx.x < 64) {            // wave 0 compacts this block's 32 rows
        const int row = min(blockIdx.x * 32 + lane, N_ROWS - 1);
        const bool act = (lane < 32) && (labels[row] >= 0) && (ious[row] > 0.5f);
        const unsigned long long mb = __ballot(act);
        const int off = __popcll(mb & ((1ull << lane) - 1ull));
        const int tot = __popcll(mb);
        int base = 0;
        if (lane == 0 && tot) base = atomicAdd(nact, tot);
        base = __shfl(base, 0);
        if (act) ridx[base + off] = row;
    }
}

// ---------------- Kernel B: fused tiled sim + mask + fixed-max softmax partials ----------------
// grid = 1024 blocks: chunk = bid&15 (512 cols), rowblk = bid>>4 (128 active-row slots)
// B tile in MFMA-FRAGMENT ORDER (zero bank conflicts, immediate-offset reads).
// Counted-vmcnt two-barrier pipeline: prefetch loads stay in flight across compute.
// launch_bounds (256,3): 4 spills the 64-VGPR A-fragments (round-14 post-mortem).
__global__ __launch_bounds__(256, 3) void main_kernel(const ushort* __restrict__ fhi,
                                                      const float* __restrict__ ious,
                                                      const int* __restrict__ labels,
                                                      const int* __restrict__ ridx,
                                                      const int* __restrict__ nact,
                                                      float* __restrict__ ps_part,
                                                      float* __restrict__ as_part) {
    const int nactive = nact[0];
    const int bid   = blockIdx.x;
    const int rbase = (bid >> 4) * R_BLK;
    if (rbase >= nactive) return;      // uniform early-exit, before any barrier

    const int chunk = bid & (N_CHUNKS - 1);
    const int c0    = chunk * C_CHUNK;

    const int tid  = threadIdx.x;
    const int lane = tid & 63;
    const int w    = tid >> 6;          // 0..3
    const int lrow = lane & 15;
    const int kg   = lane >> 4;         // 0..3
    const int s0   = rbase + w * 32;    // this wave's first row-slot

    __shared__ bf16x8 bt[2][1024];          // 32 KB, double-buffered fragment-ordered B tile
    __shared__ int    lab_s[C_CHUNK];       // 2 KB
    __shared__ float  iou_s[C_CHUNK];       // 2 KB

    // stage column metadata for this chunk (2 per thread)
#pragma unroll
    for (int i = tid; i < C_CHUNK; i += 256) {
        lab_s[i] = labels[c0 + i];
        iou_s[i] = ious[c0 + i];
    }

    // A fragments: two 16-row tiles (gathered via ridx) x 256 k in registers
    bf16x8 av0[8], av1[8];
    {
        const int rowA0 = ridx[min(s0 + lrow,      nactive - 1)];
        const int rowA1 = ridx[min(s0 + 16 + lrow, nactive - 1)];
        const ushort* pa0 = fhi + (size_t)rowA0 * DIM + kg * 8;
        const ushort* pa1 = fhi + (size_t)rowA1 * DIM + kg * 8;
#pragma unroll
        for (int t = 0; t < 8; ++t) {
            av0[t] = *reinterpret_cast<const bf16x8*>(pa0 + t * 32);
            av1[t] = *reinterpret_cast<const bf16x8*>(pa1 + t * 32);
        }
    }

    // row metadata for the 8 row-slots this lane covers (C/D: col=lane&15, row=kg*4+reg)
    int rowm[8]; int labi[8]; float ioui[8]; bool live[8];
#pragma unroll
    for (int m = 0; m < 8; ++m) {
        const int rt = m >> 2, r = m & 3;
        const int slot = s0 + rt * 16 + kg * 4 + r;
        live[m] = slot < nactive;
        const int gi = ridx[min(slot, nactive - 1)];
        rowm[m] = gi;
        labi[m] = live[m] ? labels[gi] : -2;   // -2: matches no column label
        ioui[m] = ious[gi];
    }

    float ps[8], as_[8];
#pragma unroll
    for (int m = 0; m < 8; ++m) { ps[m] = 0.f; as_[m] = 0.f; }

    // staging in fragment order: LDS chunk L <- global fragment (half,t,lr,kg2)
    const char* fhib = (const char*)fhi;
    char* btb = (char*)&bt[0][0];
    auto stage = [&](int buf, int it) {
        const int jc = c0 + it * TILE_C;
#pragma unroll
        for (int iss = 0; iss < 4; ++iss) {
            const int L    = iss * 256 + tid;      // 0..1023
            const int half = L >> 9;
            const int rem  = L & 511;
            const int t    = rem >> 6;
            const int lr   = (rem >> 2) & 15;
            const int kg2  = rem & 3;
            const char* src = fhib + (((size_t)(jc + half * 16 + lr)) << 9) + (kg2 * 16 + t * 64);
            char* dst = btb + buf * 16384 + iss * 4096 + tid * 16;
            gload_lds16(src, dst);
        }
    };

    stage(0, 0);
    __syncthreads();    // prologue: metadata ds_writes + tile0 all resident

    const float C1 = 14.42695041f;   // 10*log2(e): e = exp2(acc*C1 - C1) == exp(sim-10)
    int cur = 0;
    for (int it = 0; it < N_ITERS; ++it) {
        if (it + 1 < N_ITERS) {
            stage(cur ^ 1, it + 1);                       // 4 loads stay in flight across compute
            asm volatile("s_waitcnt vmcnt(4)" ::: "memory");  // drain tile `it` only
        } else {
            asm volatile("s_waitcnt vmcnt(0)" ::: "memory");  // last tile: full drain
        }
        __builtin_amdgcn_s_barrier();
        __builtin_amdgcn_sched_barrier(0);   // pin ds_reads below the barrier

        const int jcl = it * TILE_C;
        const int labj0 = lab_s[jcl + lrow];
        const int labj1 = lab_s[jcl + 16 + lrow];
        const float iouj0 = iou_s[jcl + lrow];
        const float iouj1 = iou_s[jcl + 16 + lrow];

        f32x4 acc00 = {0.f,0.f,0.f,0.f}, acc01 = {0.f,0.f,0.f,0.f};
        f32x4 acc10 = {0.f,0.f,0.f,0.f}, acc11 = {0.f,0.f,0.f,0.f};
        const char* lbase = btb + cur * 16384 + ((lrow * 4 + kg) << 4);
#pragma unroll
        for (int t = 0; t < 8; ++t) {
            bf16x8 b0 = *reinterpret_cast<const bf16x8*>(lbase + t * 1024);
            bf16x8 b1 = *reinterpret_cast<const bf16x8*>(lbase + 8192 + t * 1024);
            acc00 = __builtin_amdgcn_mfma_f32_16x16x32_bf16(av0[t], b0, acc00, 0, 0, 0);
            acc01 = __builtin_amdgcn_mfma_f32_16x16x32_bf16(av0[t], b1, acc01, 0, 0, 0);
            acc10 = __builtin_amdgcn_mfma_f32_16x16x32_bf16(av1[t], b0, acc10, 0, 0, 0);
            acc11 = __builtin_amdgcn_mfma_f32_16x16x32_bf16(av1[t], b1, acc11, 0, 0, 0);
        }

        // epilogue (active rows: hi_i true, ng_i false, fg_i true):
        //   pos = same && iouj>0.5 && |d|<0.2 && fgj && i!=j
        //   allm = (fgj && i!=j) && (ioum || !same)
#pragma unroll
        for (int rt = 0; rt < 2; ++rt) {
#pragma unroll
            for (int half = 0; half < 2; ++half) {
                const int colg = c0 + jcl + half * 16 + lrow;
                const int labj = half ? labj1 : labj0;
                const float iouj = half ? iouj1 : iouj0;
                const f32x4 acc = rt ? (half ? acc11 : acc10) : (half ? acc01 : acc00);
                const bool fgj = labj >= 0;
                const bool hij = iouj > 0.5f;
#pragma unroll
                for (int r = 0; r < 4; ++r) {
                    const int m  = rt * 4 + r;
                    const bool same = (labi[m] == labj);
                    const bool ioum = hij && (fabsf(iouj - ioui[m]) < 0.2f);
                    const bool pf   = fgj && (rowm[m] != colg);
                    const bool pos  = same && ioum && pf;
                    const bool allm = pf && (ioum || !same);
                    const float e = allm ? exp2f(fmaf(acc[r], C1, -C1)) : 0.0f;
                    as_[m] += e;
                    ps[m]  += pos ? e : 0.0f;
                }
            }
        }
        __builtin_amdgcn_sched_barrier(0);
        __builtin_amdgcn_s_barrier();    // reads of buf `cur` done before it+2 overwrites it
        cur ^= 1;
    }

    // reduce over the 16 lanes (lrow) holding col-slices of the same rows
#pragma unroll
    for (int off = 1; off < 16; off <<= 1) {
#pragma unroll
        for (int m = 0; m < 8; ++m) {
            ps[m]  += __shfl_xor(ps[m], off);
            as_[m] += __shfl_xor(as_[m], off);
        }
    }

    if (lrow == 0) {
#pragma unroll
        for (int m = 0; m < 8; ++m) {
            if (live[m]) {
                const int idx = chunk * N_ROWS + rowm[m];
                ps_part[idx] = ps[m];
                as_part[idx] = as_[m];
            }
        }
    }
}

// ---------------- Kernel C: combine chunk partials -> per-row loss -> mean (fused) ----------------
__global__ __launch_bounds__(256) void combine_kernel(const float* __restrict__ ps_part,
                                                      const float* __restrict__ as_part,
                                                      const float* __restrict__ ious,
                                                      const int* __restrict__ labels,
                                                      float* __restrict__ partT,
                                                      float* __restrict__ partC,
                                                      int* __restrict__ done,
                                                      float* __restrict__ out) {
    const int tid = threadIdx.x;
    const int row = blockIdx.x * 256 + tid;
    const bool act = (labels[row] >= 0) && (ious[row] > 0.5f);
    float loss = 0.f, vld = 0.f;
    if (act) {
        float P = 0.f, A = 0.f;
#pragma unroll
        for (int c = 0; c < N_CHUNKS; ++c) {
            P += ps_part[c * N_ROWS + row];
            A += as_part[c * N_ROWS + row];
        }
        const float psc = fminf(fmaxf(P, 1e-6f), 1e6f);
        const float asc = fminf(fmaxf(A, 1e-6f), 1e6f);
        const bool valid = (P > 0.0f) && (A > P);
        loss = valid ? fminf(__logf(asc) - __logf(psc), 10.0f) : 0.0f;
        vld  = valid ? 1.0f : 0.0f;
    }
    float tl = loss, tc = vld;
#pragma unroll
    for (int off = 32; off; off >>= 1) { tl += __shfl_down(tl, off); tc += __shfl_down(tc, off); }
    __shared__ float sl[4], sc[4];
    const int wid = tid >> 6;
    if ((tid & 63) == 0) { sl[wid] = tl; sc[wid] = tc; }
    __syncthreads();
    if (tid == 0) {
        partT[blockIdx.x] = sl[0] + sl[1] + sl[2] + sl[3];
        partC[blockIdx.x] = sc[0] + sc[1] + sc[2] + sc[3];
        __threadfence();
        const int prev = atomicAdd(done, 1);
        if (prev == (int)gridDim.x - 1) {      // last block finalizes (fixed order: deterministic)
            __threadfence();
            float T = 0.f, C = 0.f;
#pragma unroll
            for (int b = 0; b < N_ROWS / 256; ++b) { T += partT[b]; C += partC[b]; }
            out[0] = (C > 0.f) ? (T / C) : 0.0f;
        }
    }
}

extern "C" void kernel_launch(void* const* d_in, const int* in_sizes, int n_in,
                              void* d_out, int out_size, void* d_ws, size_t ws_size,
                              hipStream_t stream) {
    const float* feat   = (const float*)d_in[0];
    const float* ious   = (const float*)d_in[1];
    const int*   labels = (const int*)d_in[2];
    float* out = (float*)d_out;

    ushort* fhi = (ushort*)d_ws;                                     // 4 MB
    float*  ps_part = (float*)(fhi + (size_t)N_ROWS * DIM);          // 512 KB
    float*  as_part = ps_part + (size_t)N_CHUNKS * N_ROWS;           // 512 KB
    int*    ridx = (int*)(as_part + (size_t)N_CHUNKS * N_ROWS);      // 32 KB
    int*    ctrs = ridx + N_ROWS;                                    // nact, done
    float*  partT = (float*)(ctrs + 2);                              // 32 floats
    float*  partC = partT + (N_ROWS / 256);                          // 32 floats

    hipMemsetAsync(ctrs, 0, 2 * sizeof(int), stream);
    prep_kernel<<<256, 256, 0, stream>>>(feat, ious, labels, fhi, ridx, ctrs);
    main_kernel<<<(N_ROWS / R_BLK) * N_CHUNKS, 256, 0, stream>>>(fhi, ious, labels,
                                                                 ridx, ctrs, ps_part, as_part);
    combine_kernel<<<N_ROWS / 256, 256, 0, stream>>>(ps_part, as_part, ious, labels,
                                                     partT, partC, ctrs + 1, out);
}